// Round 2
// baseline (378.203 us; speedup 1.0000x reference)
//
#include <hip/hip_runtime.h>
#include <hip/hip_bf16.h>

// MultiheadAttention with relative position bias, MI355X gfx950.
// L=1024, B=16, E=512, H=8, d=64. Inputs/output fp32; ws intermediates fp16.
//
// Stage 1: qkv_kernel   -- MFMA in_proj GEMMs -> Q,K,V fp16, (B,H,L,64), q pre-scaled 1/8
//                          R9: 2-phase double-buffered global_load_lds pipeline
//                          (issue tile t+1 before computing tile t; ONE barrier/iter)
// Stage 2: transpose_v  -- V (B,H,L,64) -> Vt (B,H,64,L) for MFMA B-operand
// Stage 3: attn_kernel  -- MFMA flash attention w/ RPE bias -> CTX fp16 (L,B,E)
//                          R9: K/V de-staged (direct L2 fragment loads, barrier-free
//                          j-loop), XCD swizzle groups the 8 q-tiles of each (b,h)
// Stage 4: out_kernel   -- MFMA out_proj GEMM -> fp32 output (L,B,E), 2-phase pipeline
//
// ws (fp16 elems): Q @0, K @8M, Vt @16M, Vtmp/CTX @24M (aliased, disjoint lifetimes).
//
// MFMA f16 16x16x32 layouts (verified end-to-end in this problem, round 4):
//   A[m=lane&15][k=quad*8+j], B[k=quad*8+j][n=lane&15], D[row=quad*4+reg][col=lane&15]
//
// R8 post-mortem: SQ_LDS_BANK_CONFLICT = 8 cyc per ds_read_b128 in BOTH padded and
// swizzled layouts = the inherent 8-phase service of a 1024B read. Not a lever.
// The lever is the exposed global latency per K-iter (~6000 cyc measured vs ~400 useful).

#define L_SEQ 1024
#define B_N   16
#define E_DIM 512
#define H_N   8
#define NREL  2047

typedef _Float16 f16;
using half8   = __attribute__((ext_vector_type(8))) _Float16;
using floatx4 = __attribute__((ext_vector_type(4))) float;

__device__ __forceinline__ half8 cvt8(const float4 a, const float4 b) {
    half8 h;
    h[0] = (f16)a.x; h[1] = (f16)a.y; h[2] = (f16)a.z; h[3] = (f16)a.w;
    h[4] = (f16)b.x; h[5] = (f16)b.y; h[6] = (f16)b.z; h[7] = (f16)b.w;
    return h;
}

// async global->LDS, 16B per lane. LDS dest is wave-uniform base + lane*16.
__device__ __forceinline__ void gl_lds16(const void* g, void* l) {
    __builtin_amdgcn_global_load_lds(
        (const __attribute__((address_space(1))) unsigned int*)g,
        (__attribute__((address_space(3))) unsigned int*)l,
        16, 0, 0);
}

// ---------------------------------------------------------------------------
// Stage 1: in_proj MFMA GEMM. 1536 blocks, XCD-swizzled so the 4 f-tile
// blocks sharing an X row-slice land on one XCD (same L2).
// 2-phase pipeline: stage(t+1) issued before compute(t); one barrier per iter.
// ---------------------------------------------------------------------------
__global__ __launch_bounds__(256) void qkv_kernel(
    const float* __restrict__ Xq, const float* __restrict__ Xk, const float* __restrict__ Xv,
    const float* __restrict__ W, const float* __restrict__ Bias,
    f16* __restrict__ Qo, f16* __restrict__ Ko, f16* __restrict__ Vo)
{
    // swizzle: xcd = flat&7; 48 groups (m,proj) per XCD; 4 f-tiles per group
    const int flat = blockIdx.x;
    const int xcd  = flat & 7;
    const int slot = flat >> 3;            // 0..191
    const int g    = xcd * 48 + (slot >> 2);   // 0..383 = proj*128 + mtile
    const int f0   = (slot & 3) << 7;
    const int proj = g >> 7;               // 0=q 1=k 2=v
    const int n0   = (g & 127) << 7;

    const float* X  = (proj == 0) ? Xq : (proj == 1) ? Xk : Xv;
    const float* Wp = W + (size_t)(proj << 9) * E_DIM;

    // fp32 tiles, 128 rows x 32 f32 (128 B/row), double-buffered. 64 KB total.
    __shared__ __align__(16) float As[2][128 * 32];
    __shared__ __align__(16) float Bs[2][128 * 32];

    const int tid  = threadIdx.x;
    const int w    = tid >> 6;
    const int lane = tid & 63;
    const int quad = lane >> 4, c = lane & 15;
    const int wm = (w >> 1) << 6, wn = (w & 1) << 6;

    // staging: issue i covers rows i*32 + w*8 + (lane>>3);
    // LDS slot lane&7 holds global chunk (lane&7)^(lane>>3)  [slot s = chunk^(row&7)]
    const int lr = lane >> 3;                    // 0..7
    const int lc = (lane & 7) ^ lr;              // inverse-swizzled source chunk
    const float* Xg = X  + (size_t)(n0 + (w << 3) + lr) * E_DIM + (lc << 2);
    const float* Wg = Wp + (size_t)(f0 + (w << 3) + lr) * E_DIM + (lc << 2);

    // fragment-read swizzle: row r (r&7 == c&7), chunks 2q,2q+1 at slots ^(c&7)
    const int sa0 = (((quad << 1) ^ (c & 7)) << 2);  // f32 elem offset of first chunk
    const int sa1 = sa0 ^ 4;

    auto stage = [&](int buf, int kk) {
#pragma unroll
        for (int i = 0; i < 4; ++i) {
            gl_lds16(Xg + (size_t)i * (32 * E_DIM) + kk, &As[buf][((i << 5) + (w << 3)) << 5]);
            gl_lds16(Wg + (size_t)i * (32 * E_DIM) + kk, &Bs[buf][((i << 5) + (w << 3)) << 5]);
        }
    };

    floatx4 acc[4][4] = {};

    stage(0, 0);
    __syncthreads();                       // prologue drain: buf0 ready

    int cur = 0;
    for (int k0 = 0; k0 < E_DIM; k0 += 32) {
        if (k0 + 32 < E_DIM) stage(cur ^ 1, k0 + 32);   // fly under this tile's compute

        half8 a[4], bfr[4];
#pragma unroll
        for (int mt = 0; mt < 4; ++mt) {
            const int r = (wm + mt * 16 + c) << 5;
            const float4 lo = *reinterpret_cast<const float4*>(&As[cur][r + sa0]);
            const float4 hi = *reinterpret_cast<const float4*>(&As[cur][r + sa1]);
            a[mt] = cvt8(lo, hi);
        }
#pragma unroll
        for (int nt = 0; nt < 4; ++nt) {
            const int r = (wn + nt * 16 + c) << 5;
            const float4 lo = *reinterpret_cast<const float4*>(&Bs[cur][r + sa0]);
            const float4 hi = *reinterpret_cast<const float4*>(&Bs[cur][r + sa1]);
            bfr[nt] = cvt8(lo, hi);
        }
#pragma unroll
        for (int mt = 0; mt < 4; ++mt)
#pragma unroll
            for (int nt = 0; nt < 4; ++nt)
                acc[mt][nt] = __builtin_amdgcn_mfma_f32_16x16x32_f16(a[mt], bfr[nt], acc[mt][nt], 0, 0, 0);

        __syncthreads();                   // drains own DMA (next buf ready) + read fence
        cur ^= 1;
    }

    f16* Dst = (proj == 0) ? Qo : (proj == 1) ? Ko : Vo;
    const float scale = (proj == 0) ? 0.125f : 1.0f;

#pragma unroll
    for (int nt = 0; nt < 4; ++nt) {
        const int fl = f0 + wn + nt * 16 + c;
        const float bj = Bias[(proj << 9) + fl];
        const int h = fl >> 6, d = fl & 63;
#pragma unroll
        for (int mt = 0; mt < 4; ++mt) {
#pragma unroll
            for (int r = 0; r < 4; ++r) {
                const int n = n0 + wm + mt * 16 + quad * 4 + r;
                const int l = n >> 4, b = n & 15;
                Dst[((((size_t)b * H_N + h) * L_SEQ + l) << 6) + d] =
                    (f16)((acc[mt][nt][r] + bj) * scale);
            }
        }
    }
}

// ---------------------------------------------------------------------------
// Stage 2: V (b,h)[l][d] -> Vt (b,h)[d][l]. grid (16, 128), block 256.
// ---------------------------------------------------------------------------
__global__ __launch_bounds__(256) void transpose_v(
    const f16* __restrict__ V, f16* __restrict__ Vt)
{
    const int l0 = blockIdx.x << 6;
    const size_t base = (size_t)blockIdx.y << 16;
    __shared__ __align__(16) f16 T[64][72];
    const int tid = threadIdx.x;
    const int r = tid >> 2, co = (tid & 3) << 4;

    const uint4 a0 = *reinterpret_cast<const uint4*>(V + base + (size_t)(l0 + r) * 64 + co);
    const uint4 a1 = *reinterpret_cast<const uint4*>(V + base + (size_t)(l0 + r) * 64 + co + 8);
    *reinterpret_cast<uint4*>(&T[r][co])     = a0;
    *reinterpret_cast<uint4*>(&T[r][co + 8]) = a1;
    __syncthreads();

    union { f16 h[16]; uint4 u[2]; } pk;
#pragma unroll
    for (int j = 0; j < 16; ++j) pk.h[j] = T[co + j][r];
    *reinterpret_cast<uint4*>(Vt + base + (size_t)r * 1024 + l0 + co)     = pk.u[0];
    *reinterpret_cast<uint4*>(Vt + base + (size_t)r * 1024 + l0 + co + 8) = pk.u[1];
}

// ---------------------------------------------------------------------------
// Stage 3: MFMA flash attention, fixed-max softmax. 1024 blocks, block 256.
// R9: no K/V LDS staging -- all 4 waves read IDENTICAL fragments, so staging only
// deduped a 4x L2 re-read of a 256 KB L2-resident working set. Direct loads kill
// both j-loop barriers (waves fully independent). XCD swizzle pins the 8 q-tiles
// of each (b,h) to one XCD so K/V stay hot in its L2.
// ---------------------------------------------------------------------------
__global__ __launch_bounds__(256) void attn_kernel(
    const f16* __restrict__ Q, const f16* __restrict__ K, const f16* __restrict__ Vt,
    const int* __restrict__ RPE, const float* __restrict__ Tab, f16* __restrict__ CTX)
{
    // swizzle: xcd = flat&7; bh = (slot>>3)*8 + xcd; q-tile = slot&7
    const int flat = blockIdx.x;
    const int xcd  = flat & 7;
    const int slot = flat >> 3;            // 0..127
    const int q0   = (slot & 7) << 7;
    const int bh   = ((slot >> 3) << 3) + xcd;
    const int b = bh >> 3, h = bh & 7;

    const int tid  = threadIdx.x;
    const int w    = tid >> 6;
    const int lane = tid & 63;
    const int quad = lane >> 4, c = lane & 15;

    __shared__ __align__(16) f16 Pw[4][32][72];
    __shared__ float tab[NREL];

    const size_t base = (size_t)bh << 16;

    for (int i = tid; i < NREL; i += 256) tab[i] = Tab[h * NREL + i];

    const int qg0 = q0 + (w << 5);
    half8 Aq[2][2];
#pragma unroll
    for (int s = 0; s < 2; ++s) {
        const f16* qp = Q + base + (size_t)(qg0 + s * 16 + c) * 64 + quad * 8;
        Aq[s][0] = *reinterpret_cast<const half8*>(qp);
        Aq[s][1] = *reinterpret_cast<const half8*>(qp + 32);
    }
    __syncthreads();                       // tab ready

    floatx4 o[2][4] = {};
    float l_part[2][4] = {};

    const int* rp = RPE + (size_t)(qg0 + (quad << 2)) * 1024 + c;
    const f16* Kp = K  + base;
    const f16* Vp = Vt + base;

    for (int j0 = 0; j0 < L_SEQ; j0 += 64) {
        // direct fragment loads (all waves identical; K: 2KB contiguous/instr)
        half8 kb[4][2], vb[4][2];
#pragma unroll
        for (int nt = 0; nt < 4; ++nt) {
            const f16* kp = Kp + (size_t)(j0 + nt * 16 + c) * 64 + quad * 8;
            kb[nt][0] = *reinterpret_cast<const half8*>(kp);
            kb[nt][1] = *reinterpret_cast<const half8*>(kp + 32);
            const f16* vp = Vp + (size_t)(nt * 16 + c) * 1024 + j0 + quad * 8;
            vb[nt][0] = *reinterpret_cast<const half8*>(vp);
            vb[nt][1] = *reinterpret_cast<const half8*>(vp + 32);
        }

        int idx[2][4][4];
#pragma unroll
        for (int s = 0; s < 2; ++s)
#pragma unroll
            for (int r = 0; r < 4; ++r)
#pragma unroll
                for (int nt = 0; nt < 4; ++nt)
                    idx[s][r][nt] = rp[(size_t)(s * 16 + r) * 1024 + j0 + nt * 16];

        floatx4 sc[2][4];
#pragma unroll
        for (int nt = 0; nt < 4; ++nt) {
            floatx4 t0 = {}, t1 = {};
            t0 = __builtin_amdgcn_mfma_f32_16x16x32_f16(Aq[0][0], kb[nt][0], t0, 0, 0, 0);
            t0 = __builtin_amdgcn_mfma_f32_16x16x32_f16(Aq[0][1], kb[nt][1], t0, 0, 0, 0);
            t1 = __builtin_amdgcn_mfma_f32_16x16x32_f16(Aq[1][0], kb[nt][0], t1, 0, 0, 0);
            t1 = __builtin_amdgcn_mfma_f32_16x16x32_f16(Aq[1][1], kb[nt][1], t1, 0, 0, 0);
            sc[0][nt] = t0; sc[1][nt] = t1;
        }

#pragma unroll
        for (int s = 0; s < 2; ++s)
#pragma unroll
            for (int r = 0; r < 4; ++r) {
                float rs = 0.0f;
#pragma unroll
                for (int nt = 0; nt < 4; ++nt) {
                    const float p = __expf(sc[s][nt][r] + tab[idx[s][r][nt]]);
                    rs += p;
                    Pw[w][s * 16 + quad * 4 + r][nt * 16 + c] = (f16)p;
                }
                l_part[s][r] += rs;
            }

#pragma unroll
        for (int s = 0; s < 2; ++s) {
            const half8 Ap0 = *reinterpret_cast<const half8*>(&Pw[w][s * 16 + c][quad * 8]);
            const half8 Ap1 = *reinterpret_cast<const half8*>(&Pw[w][s * 16 + c][32 + quad * 8]);
#pragma unroll
            for (int nt = 0; nt < 4; ++nt) {
                o[s][nt] = __builtin_amdgcn_mfma_f32_16x16x32_f16(Ap0, vb[nt][0], o[s][nt], 0, 0, 0);
                o[s][nt] = __builtin_amdgcn_mfma_f32_16x16x32_f16(Ap1, vb[nt][1], o[s][nt], 0, 0, 0);
            }
        }
    }

#pragma unroll
    for (int s = 0; s < 2; ++s)
#pragma unroll
        for (int r = 0; r < 4; ++r) {
            float l = l_part[s][r];
            l += __shfl_xor(l, 1); l += __shfl_xor(l, 2);
            l += __shfl_xor(l, 4); l += __shfl_xor(l, 8);
            const float inv = 1.0f / l;
            const int lrow = qg0 + s * 16 + quad * 4 + r;
            f16* dp = CTX + ((size_t)(lrow * 16 + b)) * 512 + h * 64;
#pragma unroll
            for (int nt = 0; nt < 4; ++nt)
                dp[nt * 16 + c] = (f16)(o[s][nt][r] * inv);
        }
}

// ---------------------------------------------------------------------------
// Stage 4: out_proj MFMA GEMM. 512 blocks, XCD-swizzled, 2-phase pipeline.
// A = CTX (f16, DMA direct); B = W (fp32, DMA + read-path convert).
// ---------------------------------------------------------------------------
__global__ __launch_bounds__(256) void out_kernel(
    const f16* __restrict__ X, const float* __restrict__ W, const float* __restrict__ Bias,
    float* __restrict__ Out)
{
    // swizzle: 16 m-groups per XCD, 4 f-tiles per group on same XCD
    const int flat = blockIdx.x;
    const int xcd  = flat & 7;
    const int slot = flat >> 3;            // 0..63
    const int m    = xcd * 16 + (slot >> 2);   // 0..127
    const int f0   = (slot & 3) << 7;
    const int n0   = m << 7;

    // A: f16 tile 128x32 (64 B/row, 4 chunks). B: fp32 tile 128x32 (128 B/row). 48 KB.
    __shared__ __align__(16) f16   As[2][128 * 32];
    __shared__ __align__(16) float Bs[2][128 * 32];

    const int tid  = threadIdx.x;
    const int w    = tid >> 6;
    const int lane = tid & 63;
    const int quad = lane >> 4, c = lane & 15;
    const int wm = (w >> 1) << 6, wn = (w & 1) << 6;

    // A staging: issue i covers rows i*64 + w*16 + (lane>>2); slot lane&3 holds
    // logical chunk (lane&3)^((lane>>3)&3)   [f16 swizzle: slot = c ^ ((row>>1)&3)]
    const int ar  = lane >> 2;                       // 0..15
    const int ac  = (lane & 3) ^ ((lane >> 3) & 3);  // source chunk (8 f16)
    const f16* Xg = X + (size_t)(n0 + (w << 4) + ar) * E_DIM + (ac << 3);

    // B staging: same as qkv (fp32, slot = c ^ (row&7))
    const int lr = lane >> 3;
    const int lc = (lane & 7) ^ lr;
    const float* Wg = W + (size_t)(f0 + (w << 3) + lr) * E_DIM + (lc << 2);

    // read swizzles
    const int sa = ((quad ^ ((c >> 1) & 3)) << 3);   // f16 elem offset in A row
    const int sb0 = (((quad << 1) ^ (c & 7)) << 2);  // f32 elem offset in B row
    const int sb1 = sb0 ^ 4;

    auto stage = [&](int buf, int kk) {
#pragma unroll
        for (int i = 0; i < 2; ++i)
            gl_lds16(Xg + (size_t)i * (64 * E_DIM) + kk, &As[buf][((i << 6) + (w << 4)) << 5]);
#pragma unroll
        for (int i = 0; i < 4; ++i)
            gl_lds16(Wg + (size_t)i * (32 * E_DIM) + kk, &Bs[buf][((i << 5) + (w << 3)) << 5]);
    };

    floatx4 acc[4][4] = {};

    stage(0, 0);
    __syncthreads();

    int cur = 0;
    for (int k0 = 0; k0 < E_DIM; k0 += 32) {
        if (k0 + 32 < E_DIM) stage(cur ^ 1, k0 + 32);

        half8 a[4], bfr[4];
#pragma unroll
        for (int mt = 0; mt < 4; ++mt) {
            const int r = (wm + mt * 16 + c) << 5;
            a[mt] = *reinterpret_cast<const half8*>(&As[cur][r + sa]);
        }
#pragma unroll
        for (int nt = 0; nt < 4; ++nt) {
            const int r = (wn + nt * 16 + c) << 5;
            const float4 lo = *reinterpret_cast<const float4*>(&Bs[cur][r + sb0]);
            const float4 hi = *reinterpret_cast<const float4*>(&Bs[cur][r + sb1]);
            bfr[nt] = cvt8(lo, hi);
        }
#pragma unroll
        for (int mt = 0; mt < 4; ++mt)
#pragma unroll
            for (int nt = 0; nt < 4; ++nt)
                acc[mt][nt] = __builtin_amdgcn_mfma_f32_16x16x32_f16(a[mt], bfr[nt], acc[mt][nt], 0, 0, 0);

        __syncthreads();
        cur ^= 1;
    }

#pragma unroll
    for (int nt = 0; nt < 4; ++nt) {
        const int f = f0 + wn + nt * 16 + c;
        const float bj = Bias[f];
#pragma unroll
        for (int mt = 0; mt < 4; ++mt) {
#pragma unroll
            for (int r = 0; r < 4; ++r) {
                const int n = n0 + wm + mt * 16 + quad * 4 + r;
                Out[(size_t)n * E_DIM + f] = acc[mt][nt][r] + bj;
            }
        }
    }
}

// ---------------------------------------------------------------------------
extern "C" void kernel_launch(void* const* d_in, const int* in_sizes, int n_in,
                              void* d_out, int out_size, void* d_ws, size_t ws_size,
                              hipStream_t stream) {
    const float* q_in = (const float*)d_in[0];
    const float* k_in = (const float*)d_in[1];
    const float* v_in = (const float*)d_in[2];
    const float* ipw  = (const float*)d_in[3];
    const float* ipb  = (const float*)d_in[4];
    const float* opw  = (const float*)d_in[5];
    const float* opb  = (const float*)d_in[6];
    const float* tab  = (const float*)d_in[7];
    const int*   rpe  = (const int*)d_in[8];
    float* out = (float*)d_out;

    f16* ws   = (f16*)d_ws;
    f16* Q    = ws;
    f16* K    = ws + 8388608;
    f16* Vt   = ws + 16777216;
    f16* Vtmp = ws + 25165824;
    f16* CTX  = ws + 25165824;

    qkv_kernel<<<dim3(1536), 256, 0, stream>>>(q_in, k_in, v_in, ipw, ipb, Q, K, Vtmp);
    transpose_v<<<dim3(16, 128), 256, 0, stream>>>(Vtmp, Vt);
    attn_kernel<<<dim3(1024), 256, 0, stream>>>(Q, K, Vt, rpe, tab, CTX);
    out_kernel<<<dim3(512), 256, 0, stream>>>(CTX, opw, opb, out);
}

// Round 3
// 308.928 us; speedup vs baseline: 1.2242x; 1.2242x over previous
//
#include <hip/hip_runtime.h>
#include <hip/hip_bf16.h>

// MultiheadAttention with relative position bias, MI355X gfx950.
// L=1024, B=16, E=512, H=8, d=64. Inputs/output fp32; ws intermediates fp16.
//
// Stage 1: qkv_kernel   -- MFMA in_proj GEMMs -> Q,K,V fp16, (B,H,L,64), q pre-scaled 1/8
//                          R10: f16 reg-staged LDS (cvt at write), padded [128][40],
//                          raw-barrier pipeline w/ loads in flight across barriers
// Stage 2: transpose_v  -- V (B,H,L,64) -> Vt (B,H,64,L) for MFMA B-operand
// Stage 3: attn_kernel  -- MFMA flash attention w/ RPE bias -> CTX fp16 (L,B,E)
//                          R10: REVERT to R1 staged K/V body (94us) + keep XCD swizzle
// Stage 4: out_kernel   -- MFMA out_proj GEMM -> fp32 output (L,B,E), same R10 pipeline
//
// ws (fp16 elems): Q @0, K @8M, Vt @16M, Vtmp/CTX @24M (aliased, disjoint lifetimes).
//
// MFMA f16 16x16x32 layouts (verified end-to-end in this problem, round 4):
//   A[m=lane&15][k=quad*8+j], B[k=quad*8+j][n=lane&15], D[row=quad*4+reg][col=lane&15]
//
// R9 post-mortem: __syncthreads' implicit vmcnt(0) drains DMA issued ~350cy earlier
// vs ~900cy latency -> exposed stall each iter; fp32 LDS tiles cost 2x ds_read + 64
// read-path cvts. Fix: f16 tiles (cvt once at stage) + raw s_barrier + lgkmcnt(0)
// (sched_barrier-pinned) so global loads survive the barrier with ~1 full iter cover.

#define L_SEQ 1024
#define B_N   16
#define E_DIM 512
#define H_N   8
#define NREL  2047

typedef _Float16 f16;
using half4   = __attribute__((ext_vector_type(4))) _Float16;
using half8   = __attribute__((ext_vector_type(8))) _Float16;
using floatx4 = __attribute__((ext_vector_type(4))) float;

// lgkmcnt(0) drain (ds_write visibility) + raw barrier, pinned against code motion.
// Does NOT drain vmcnt -> global loads stay in flight across the barrier.
#define LGKM_BARRIER() do {                                   \
    asm volatile("s_waitcnt lgkmcnt(0)" ::: "memory");        \
    __builtin_amdgcn_sched_barrier(0);                        \
    __builtin_amdgcn_s_barrier();                             \
    __builtin_amdgcn_sched_barrier(0);                        \
} while (0)

__device__ __forceinline__ half4 cvt4(const float4 a) {
    half4 h;
    h[0] = (f16)a.x; h[1] = (f16)a.y; h[2] = (f16)a.z; h[3] = (f16)a.w;
    return h;
}

// ---------------------------------------------------------------------------
// Stage 1: in_proj MFMA GEMM. 1536 blocks, XCD-swizzled so the 4 f-tile
// blocks sharing an X row-slice land on one XCD (same L2).
// Pipeline per iter: compute(buf[t&1]) ; cvt+write(t+1) ; issue loads(t+2) ;
// lgkmcnt(0)+s_barrier.  Loads issued at iter t are consumed at iter t+1's
// write phase -> ~1 barrier + 1 compute phase of latency cover.
// ---------------------------------------------------------------------------
__global__ __launch_bounds__(256) void qkv_kernel(
    const float* __restrict__ Xq, const float* __restrict__ Xk, const float* __restrict__ Xv,
    const float* __restrict__ W, const float* __restrict__ Bias,
    f16* __restrict__ Qo, f16* __restrict__ Ko, f16* __restrict__ Vo)
{
    // swizzle: xcd = flat&7; 48 groups (m,proj) per XCD; 4 f-tiles per group
    const int flat = blockIdx.x;
    const int xcd  = flat & 7;
    const int slot = flat >> 3;            // 0..191
    const int g    = xcd * 48 + (slot >> 2);   // 0..383 = proj*128 + mtile
    const int f0   = (slot & 3) << 7;
    const int proj = g >> 7;               // 0=q 1=k 2=v
    const int n0   = (g & 127) << 7;

    const float* X  = (proj == 0) ? Xq : (proj == 1) ? Xk : Xv;
    const float* Wp = W + (size_t)(proj << 9) * E_DIM;

    // f16 tiles, padded rows (40 f16 = 80 B -> bank spread), double-buffered. 40 KB.
    __shared__ __align__(16) f16 As[2][128][40];
    __shared__ __align__(16) f16 Bs[2][128][40];

    const int tid  = threadIdx.x;
    const int w    = tid >> 6;
    const int lane = tid & 63;
    const int quad = lane >> 4, c = lane & 15;
    const int wm = (w >> 1) << 6, wn = (w & 1) << 6;

    // staging: wave w covers rows [w*32, w*32+32); instr i: row = w*32+i*8+(lane>>3),
    // cols (lane&7)*4 .. +3 (fp32) -> 8 rows x 128 B contiguous segments per instr.
    const int srow = (w << 5) + (lane >> 3);     // + i*8
    const int scol = (lane & 7) << 2;
    const float* Xg = X  + (size_t)(n0 + srow) * E_DIM + scol;
    const float* Wg = Wp + (size_t)(f0 + srow) * E_DIM + scol;

    float4 lx[4], lw[4];
    auto load_tile = [&](int kk) {
#pragma unroll
        for (int i = 0; i < 4; ++i)
            lx[i] = *reinterpret_cast<const float4*>(Xg + (size_t)(i * 8) * E_DIM + kk);
#pragma unroll
        for (int i = 0; i < 4; ++i)
            lw[i] = *reinterpret_cast<const float4*>(Wg + (size_t)(i * 8) * E_DIM + kk);
    };
    auto write_tile = [&](int buf) {
#pragma unroll
        for (int i = 0; i < 4; ++i)
            *reinterpret_cast<half4*>(&As[buf][srow + i * 8][scol]) = cvt4(lx[i]);
#pragma unroll
        for (int i = 0; i < 4; ++i)
            *reinterpret_cast<half4*>(&Bs[buf][srow + i * 8][scol]) = cvt4(lw[i]);
    };

    floatx4 acc[4][4] = {};

    // prologue: tile0 staged+visible; tile1 loads in flight
    load_tile(0);
    write_tile(0);
    load_tile(32);
    LGKM_BARRIER();

    for (int t = 0; t < 16; ++t) {
        const int cur = t & 1;

        half8 a[4], bfr[4];
#pragma unroll
        for (int mt = 0; mt < 4; ++mt)
            a[mt] = *reinterpret_cast<const half8*>(&As[cur][wm + mt * 16 + c][quad * 8]);
#pragma unroll
        for (int nt = 0; nt < 4; ++nt)
            bfr[nt] = *reinterpret_cast<const half8*>(&Bs[cur][wn + nt * 16 + c][quad * 8]);
#pragma unroll
        for (int mt = 0; mt < 4; ++mt)
#pragma unroll
            for (int nt = 0; nt < 4; ++nt)
                acc[mt][nt] = __builtin_amdgcn_mfma_f32_16x16x32_f16(a[mt], bfr[nt], acc[mt][nt], 0, 0, 0);

        if (t < 15) {
            write_tile(cur ^ 1);               // cvt consumes loads(t+1); auto vmcnt wait
            if (t < 14) load_tile((t + 2) * 32);  // regs free -> issue next, flies over barrier
        }
        LGKM_BARRIER();
    }

    f16* Dst = (proj == 0) ? Qo : (proj == 1) ? Ko : Vo;
    const float scale = (proj == 0) ? 0.125f : 1.0f;

#pragma unroll
    for (int nt = 0; nt < 4; ++nt) {
        const int fl = f0 + wn + nt * 16 + c;
        const float bj = Bias[(proj << 9) + fl];
        const int h = fl >> 6, d = fl & 63;
#pragma unroll
        for (int mt = 0; mt < 4; ++mt) {
#pragma unroll
            for (int r = 0; r < 4; ++r) {
                const int n = n0 + wm + mt * 16 + quad * 4 + r;
                const int l = n >> 4, b = n & 15;
                Dst[((((size_t)b * H_N + h) * L_SEQ + l) << 6) + d] =
                    (f16)((acc[mt][nt][r] + bj) * scale);
            }
        }
    }
}

// ---------------------------------------------------------------------------
// Stage 2: V (b,h)[l][d] -> Vt (b,h)[d][l]. grid (16, 128), block 256.
// ---------------------------------------------------------------------------
__global__ __launch_bounds__(256) void transpose_v(
    const f16* __restrict__ V, f16* __restrict__ Vt)
{
    const int l0 = blockIdx.x << 6;
    const size_t base = (size_t)blockIdx.y << 16;
    __shared__ __align__(16) f16 T[64][72];
    const int tid = threadIdx.x;
    const int r = tid >> 2, co = (tid & 3) << 4;

    const uint4 a0 = *reinterpret_cast<const uint4*>(V + base + (size_t)(l0 + r) * 64 + co);
    const uint4 a1 = *reinterpret_cast<const uint4*>(V + base + (size_t)(l0 + r) * 64 + co + 8);
    *reinterpret_cast<uint4*>(&T[r][co])     = a0;
    *reinterpret_cast<uint4*>(&T[r][co + 8]) = a1;
    __syncthreads();

    union { f16 h[16]; uint4 u[2]; } pk;
#pragma unroll
    for (int j = 0; j < 16; ++j) pk.h[j] = T[co + j][r];
    *reinterpret_cast<uint4*>(Vt + base + (size_t)r * 1024 + l0 + co)     = pk.u[0];
    *reinterpret_cast<uint4*>(Vt + base + (size_t)r * 1024 + l0 + co + 8) = pk.u[1];
}

// ---------------------------------------------------------------------------
// Stage 3: MFMA flash attention, fixed-max softmax. 1024 blocks, block 256.
// R10: revert to R1 staged K/V body (uint4 reg prefetch, 2 syncs/iter) -- the
// R9 de-staging serialized L2 latency and cost +56us. Keep XCD swizzle (halved
// HBM fetch in R9: the 8 q-tile blocks of each (b,h) share K/V through one L2).
// ---------------------------------------------------------------------------
__global__ __launch_bounds__(256, 3) void attn_kernel(
    const f16* __restrict__ Q, const f16* __restrict__ K, const f16* __restrict__ Vt,
    const int* __restrict__ RPE, const float* __restrict__ Tab, f16* __restrict__ CTX)
{
    // swizzle: xcd = flat&7; bh = (slot>>3)*8 + xcd; q-tile = slot&7
    const int flat = blockIdx.x;
    const int xcd  = flat & 7;
    const int slot = flat >> 3;            // 0..127
    const int q0   = (slot & 7) << 7;
    const int bh   = ((slot >> 3) << 3) + xcd;
    const int b = bh >> 3, h = bh & 7;

    const int tid  = threadIdx.x;
    const int w    = tid >> 6;
    const int lane = tid & 63;
    const int quad = lane >> 4, c = lane & 15;

    __shared__ __align__(16) f16 Ks[64][72];
    __shared__ __align__(16) f16 Vts[64][72];
    __shared__ __align__(16) f16 Pw[4][32][72];
    __shared__ float tab[NREL];

    const size_t base = (size_t)bh << 16;

    for (int i = tid; i < NREL; i += 256) tab[i] = Tab[h * NREL + i];

    const int qg0 = q0 + (w << 5);
    half8 Aq[2][2];
#pragma unroll
    for (int s = 0; s < 2; ++s) {
        const f16* qp = Q + base + (size_t)(qg0 + s * 16 + c) * 64 + quad * 8;
        Aq[s][0] = *reinterpret_cast<const half8*>(qp);
        Aq[s][1] = *reinterpret_cast<const half8*>(qp + 32);
    }

    floatx4 o[2][4] = {};
    float l_part[2][4] = {};

    const int* rp = RPE + (size_t)(qg0 + (quad << 2)) * 1024 + c;

    const int sr = tid >> 2, so = (tid & 3) << 4;
    const f16* kbase = K  + base + (size_t)sr * 64 + so;
    const f16* vbase = Vt + base + (size_t)sr * 1024 + so;

    uint4 pk0 = *reinterpret_cast<const uint4*>(kbase);
    uint4 pk1 = *reinterpret_cast<const uint4*>(kbase + 8);
    uint4 pv0 = *reinterpret_cast<const uint4*>(vbase);
    uint4 pv1 = *reinterpret_cast<const uint4*>(vbase + 8);

    for (int j0 = 0; j0 < L_SEQ; j0 += 64) {
        __syncthreads();
        *reinterpret_cast<uint4*>(&Ks[sr][so])      = pk0;
        *reinterpret_cast<uint4*>(&Ks[sr][so + 8])  = pk1;
        *reinterpret_cast<uint4*>(&Vts[sr][so])     = pv0;
        *reinterpret_cast<uint4*>(&Vts[sr][so + 8]) = pv1;
        __syncthreads();

        if (j0 + 64 < L_SEQ) {
            const f16* kn = kbase + (size_t)(j0 + 64) * 64;
            const f16* vn = vbase + (j0 + 64);
            pk0 = *reinterpret_cast<const uint4*>(kn);
            pk1 = *reinterpret_cast<const uint4*>(kn + 8);
            pv0 = *reinterpret_cast<const uint4*>(vn);
            pv1 = *reinterpret_cast<const uint4*>(vn + 8);
        }

        int idx[2][4][4];
#pragma unroll
        for (int s = 0; s < 2; ++s)
#pragma unroll
            for (int r = 0; r < 4; ++r)
#pragma unroll
                for (int nt = 0; nt < 4; ++nt)
                    idx[s][r][nt] = rp[(size_t)(s * 16 + r) * 1024 + j0 + nt * 16];

        floatx4 sc[2][4];
#pragma unroll
        for (int nt = 0; nt < 4; ++nt) {
            const half8 b0 = *reinterpret_cast<const half8*>(&Ks[nt * 16 + c][quad * 8]);
            const half8 b1 = *reinterpret_cast<const half8*>(&Ks[nt * 16 + c][32 + quad * 8]);
            floatx4 t0 = {}, t1 = {};
            t0 = __builtin_amdgcn_mfma_f32_16x16x32_f16(Aq[0][0], b0, t0, 0, 0, 0);
            t0 = __builtin_amdgcn_mfma_f32_16x16x32_f16(Aq[0][1], b1, t0, 0, 0, 0);
            t1 = __builtin_amdgcn_mfma_f32_16x16x32_f16(Aq[1][0], b0, t1, 0, 0, 0);
            t1 = __builtin_amdgcn_mfma_f32_16x16x32_f16(Aq[1][1], b1, t1, 0, 0, 0);
            sc[0][nt] = t0; sc[1][nt] = t1;
        }

#pragma unroll
        for (int s = 0; s < 2; ++s)
#pragma unroll
            for (int r = 0; r < 4; ++r) {
                float rs = 0.0f;
#pragma unroll
                for (int nt = 0; nt < 4; ++nt) {
                    const float p = __expf(sc[s][nt][r] + tab[idx[s][r][nt]]);
                    rs += p;
                    Pw[w][s * 16 + quad * 4 + r][nt * 16 + c] = (f16)p;
                }
                l_part[s][r] += rs;
            }

        half8 vb[4][2];
#pragma unroll
        for (int nt = 0; nt < 4; ++nt) {
            vb[nt][0] = *reinterpret_cast<const half8*>(&Vts[nt * 16 + c][quad * 8]);
            vb[nt][1] = *reinterpret_cast<const half8*>(&Vts[nt * 16 + c][32 + quad * 8]);
        }
#pragma unroll
        for (int s = 0; s < 2; ++s) {
            const half8 Ap0 = *reinterpret_cast<const half8*>(&Pw[w][s * 16 + c][quad * 8]);
            const half8 Ap1 = *reinterpret_cast<const half8*>(&Pw[w][s * 16 + c][32 + quad * 8]);
#pragma unroll
            for (int nt = 0; nt < 4; ++nt) {
                o[s][nt] = __builtin_amdgcn_mfma_f32_16x16x32_f16(Ap0, vb[nt][0], o[s][nt], 0, 0, 0);
                o[s][nt] = __builtin_amdgcn_mfma_f32_16x16x32_f16(Ap1, vb[nt][1], o[s][nt], 0, 0, 0);
            }
        }
    }

#pragma unroll
    for (int s = 0; s < 2; ++s)
#pragma unroll
        for (int r = 0; r < 4; ++r) {
            float l = l_part[s][r];
            l += __shfl_xor(l, 1); l += __shfl_xor(l, 2);
            l += __shfl_xor(l, 4); l += __shfl_xor(l, 8);
            const float inv = 1.0f / l;
            const int lrow = qg0 + s * 16 + quad * 4 + r;
            f16* dp = CTX + ((size_t)(lrow * 16 + b)) * 512 + h * 64;
#pragma unroll
            for (int nt = 0; nt < 4; ++nt)
                dp[nt * 16 + c] = (f16)(o[s][nt][r] * inv);
        }
}

// ---------------------------------------------------------------------------
// Stage 4: out_proj MFMA GEMM. 512 blocks, XCD-swizzled, R10 pipeline.
// A = CTX (f16 pass-through regs); B = W (fp32 -> cvt at write).
// ---------------------------------------------------------------------------
__global__ __launch_bounds__(256) void out_kernel(
    const f16* __restrict__ X, const float* __restrict__ W, const float* __restrict__ Bias,
    float* __restrict__ Out)
{
    // swizzle: 16 m-groups per XCD, 4 f-tiles per group on same XCD
    const int flat = blockIdx.x;
    const int xcd  = flat & 7;
    const int slot = flat >> 3;            // 0..63
    const int m    = xcd * 16 + (slot >> 2);   // 0..127
    const int f0   = (slot & 3) << 7;
    const int n0   = m << 7;

    __shared__ __align__(16) f16 As[2][128][40];
    __shared__ __align__(16) f16 Bs[2][128][40];

    const int tid  = threadIdx.x;
    const int w    = tid >> 6;
    const int lane = tid & 63;
    const int quad = lane >> 4, c = lane & 15;
    const int wm = (w >> 1) << 6, wn = (w & 1) << 6;

    // A staging (f16): instr i: row = w*32 + i*16 + (lane>>2), col = (lane&3)*8
    const int arow = (w << 5) + (lane >> 2);     // + i*16
    const int acol = (lane & 3) << 3;
    const f16* Xg = X + (size_t)(n0 + arow) * E_DIM + acol;

    // B staging (fp32): as qkv
    const int srow = (w << 5) + (lane >> 3);     // + i*8
    const int scol = (lane & 7) << 2;
    const float* Wg = W + (size_t)(f0 + srow) * E_DIM + scol;

    uint4  la[2];
    float4 lw[4];
    auto load_tile = [&](int kk) {
#pragma unroll
        for (int i = 0; i < 2; ++i)
            la[i] = *reinterpret_cast<const uint4*>(Xg + (size_t)(i * 16) * E_DIM + kk);
#pragma unroll
        for (int i = 0; i < 4; ++i)
            lw[i] = *reinterpret_cast<const float4*>(Wg + (size_t)(i * 8) * E_DIM + kk);
    };
    auto write_tile = [&](int buf) {
#pragma unroll
        for (int i = 0; i < 2; ++i)
            *reinterpret_cast<uint4*>(&As[buf][arow + i * 16][acol]) = la[i];
#pragma unroll
        for (int i = 0; i < 4; ++i)
            *reinterpret_cast<half4*>(&Bs[buf][srow + i * 8][scol]) = cvt4(lw[i]);
    };

    floatx4 acc[4][4] = {};

    load_tile(0);
    write_tile(0);
    load_tile(32);
    LGKM_BARRIER();

    for (int t = 0; t < 16; ++t) {
        const int cur = t & 1;

        half8 a[4], bfr[4];
#pragma unroll
        for (int mt = 0; mt < 4; ++mt)
            a[mt] = *reinterpret_cast<const half8*>(&As[cur][wm + mt * 16 + c][quad * 8]);
#pragma unroll
        for (int nt = 0; nt < 4; ++nt)
            bfr[nt] = *reinterpret_cast<const half8*>(&Bs[cur][wn + nt * 16 + c][quad * 8]);
#pragma unroll
        for (int mt = 0; mt < 4; ++mt)
#pragma unroll
            for (int nt = 0; nt < 4; ++nt)
                acc[mt][nt] = __builtin_amdgcn_mfma_f32_16x16x32_f16(a[mt], bfr[nt], acc[mt][nt], 0, 0, 0);

        if (t < 15) {
            write_tile(cur ^ 1);
            if (t < 14) load_tile((t + 2) * 32);
        }
        LGKM_BARRIER();
    }

#pragma unroll
    for (int nt = 0; nt < 4; ++nt) {
        const int f = f0 + wn + nt * 16 + c;
        const float bj = Bias[f];
#pragma unroll
        for (int mt = 0; mt < 4; ++mt) {
#pragma unroll
            for (int r = 0; r < 4; ++r) {
                const int n = n0 + wm + mt * 16 + quad * 4 + r;
                Out[(size_t)n * E_DIM + f] = acc[mt][nt][r] + bj;
            }
        }
    }
}

// ---------------------------------------------------------------------------
extern "C" void kernel_launch(void* const* d_in, const int* in_sizes, int n_in,
                              void* d_out, int out_size, void* d_ws, size_t ws_size,
                              hipStream_t stream) {
    const float* q_in = (const float*)d_in[0];
    const float* k_in = (const float*)d_in[1];
    const float* v_in = (const float*)d_in[2];
    const float* ipw  = (const float*)d_in[3];
    const float* ipb  = (const float*)d_in[4];
    const float* opw  = (const float*)d_in[5];
    const float* opb  = (const float*)d_in[6];
    const float* tab  = (const float*)d_in[7];
    const int*   rpe  = (const int*)d_in[8];
    float* out = (float*)d_out;

    f16* ws   = (f16*)d_ws;
    f16* Q    = ws;
    f16* K    = ws + 8388608;
    f16* Vt   = ws + 16777216;
    f16* Vtmp = ws + 25165824;
    f16* CTX  = ws + 25165824;

    qkv_kernel<<<dim3(1536), 256, 0, stream>>>(q_in, k_in, v_in, ipw, ipb, Q, K, Vtmp);
    transpose_v<<<dim3(16, 128), 256, 0, stream>>>(Vtmp, Vt);
    attn_kernel<<<dim3(1024), 256, 0, stream>>>(Q, K, Vt, rpe, tab, CTX);
    out_kernel<<<dim3(512), 256, 0, stream>>>(CTX, opw, opb, out);
}